// Round 1
// baseline (272.133 us; speedup 1.0000x reference)
//
#include <hip/hip_runtime.h>
#include <math.h>

#define EMB 768
#define NSCEN 19
#define SDIM 16
#define CD 64          // hidden cols
#define BM 256         // rows per block
#define KT 32          // K chunk
#define KBAG 20        // bag chunk (19 scenarios + 1 zero pad row)
#define AS_STRIDE 260  // BM + 4 pad: byte stride 1040 (16B-aligned, bank-shift 4)

// P[s][j] = sum_d table[s][d] * W1[768 + s*16 + d][j]; rows 19 zeroed.
__global__ void compute_P(const float* __restrict__ table,
                          const float* __restrict__ W1,
                          float* __restrict__ P) {
    int t = threadIdx.x;
    for (int e = t; e < KBAG * CD; e += 256) {
        int s = e >> 6, j = e & 63;
        float acc = 0.f;
        if (s < NSCEN) {
#pragma unroll
            for (int d = 0; d < SDIM; ++d)
                acc += table[s * SDIM + d] * W1[(size_t)(EMB + s * SDIM + d) * CD + j];
        }
        P[e] = acc;
    }
}

__global__ __launch_bounds__(256, 2)
void scorer_main(const float* __restrict__ emb,
                 const int* __restrict__ ids,
                 const float* __restrict__ mask,
                 const float* __restrict__ P,
                 const float* __restrict__ W1,
                 const float* __restrict__ b1,
                 const float* __restrict__ W2,
                 const float* __restrict__ b2,
                 float* __restrict__ out) {
    __shared__ float As[KT][AS_STRIDE];    // emb chunk, transposed [k][row]
    __shared__ float AsX[KBAG][AS_STRIDE]; // bag weights [s][row]
    __shared__ float Bs[KT][CD];           // W1 chunk [k][col] (also reused for P)
    __shared__ float b1s[CD], w2s[CD];

    const int t = threadIdx.x;
    const int row0 = blockIdx.x * BM;

    if (t < CD) { b1s[t] = b1[t]; w2s[t] = W2[t]; }

    // ---- Prologue: bag weights. Thread t owns row (row0+t), column t of AsX.
    {
        const int r = t;
#pragma unroll
        for (int s = 0; s < KBAG; ++s) AsX[s][r] = 0.f;
        const int*   idrow = ids  + (size_t)(row0 + r) * 32;
        const float* mrow  = mask + (size_t)(row0 + r) * 32;
        float cnt = 0.f;
#pragma unroll
        for (int w = 0; w < 32; ++w) {
            int s = idrow[w];
            float m = mrow[w];
            AsX[s][r] += m;   // exclusive column: no race
            cnt += m;
        }
        float rc = 1.0f / fmaxf(cnt, 1.0f);
#pragma unroll
        for (int s = 0; s < NSCEN; ++s) AsX[s][r] *= rc;
    }

    const int tx = t & 7;   // col group: cols tx*8 .. +7
    const int ty = t >> 3;  // row group: rows ty*8 .. +7

    float acc[8][8];
#pragma unroll
    for (int i = 0; i < 8; ++i)
#pragma unroll
        for (int j = 0; j < 8; ++j) acc[i][j] = 0.f;

    // ---- Main K loop over the 768 embedding dims
    for (int kc = 0; kc < EMB / KT; ++kc) {
        const int k0 = kc * KT;
        // stage As: thread t loads 32 consecutive floats of its own row,
        // scatters transposed (write banks (4k + r)%32, r spans 64 lanes -> 2-way, free)
        {
            const float4* src = (const float4*)(emb + (size_t)(row0 + t) * EMB + k0);
#pragma unroll
            for (int q = 0; q < 8; ++q) {
                float4 v = src[q];
                As[q * 4 + 0][t] = v.x;
                As[q * 4 + 1][t] = v.y;
                As[q * 4 + 2][t] = v.z;
                As[q * 4 + 3][t] = v.w;
            }
        }
        // stage Bs: W1 rows k0..k0+31 (coalesced float4)
        {
#pragma unroll
            for (int p = 0; p < 2; ++p) {
                int k  = p * 16 + (t >> 4);
                int j4 = (t & 15) * 4;
                *(float4*)(&Bs[k][j4]) =
                    *(const float4*)(W1 + (size_t)(k0 + k) * CD + j4);
            }
        }
        __syncthreads();
#pragma unroll
        for (int k = 0; k < KT; ++k) {
            float4 a0  = *(const float4*)(&As[k][ty * 8]);
            float4 a1  = *(const float4*)(&As[k][ty * 8 + 4]);
            float4 bq0 = *(const float4*)(&Bs[k][tx * 8]);
            float4 bq1 = *(const float4*)(&Bs[k][tx * 8 + 4]);
            float av[8] = {a0.x, a0.y, a0.z, a0.w, a1.x, a1.y, a1.z, a1.w};
            float bv[8] = {bq0.x, bq0.y, bq0.z, bq0.w, bq1.x, bq1.y, bq1.z, bq1.w};
#pragma unroll
            for (int i = 0; i < 8; ++i)
#pragma unroll
                for (int j = 0; j < 8; ++j)
                    acc[i][j] = fmaf(av[i], bv[j], acc[i][j]);
        }
        __syncthreads();
    }

    // ---- Bag chunk: A from AsX, B = P staged into Bs
    for (int e = t; e < (KBAG * CD) / 4; e += 256)
        ((float4*)&Bs[0][0])[e] = ((const float4*)P)[e];
    __syncthreads();
#pragma unroll
    for (int k = 0; k < KBAG; ++k) {
        float4 a0  = *(const float4*)(&AsX[k][ty * 8]);
        float4 a1  = *(const float4*)(&AsX[k][ty * 8 + 4]);
        float4 bq0 = *(const float4*)(&Bs[k][tx * 8]);
        float4 bq1 = *(const float4*)(&Bs[k][tx * 8 + 4]);
        float av[8] = {a0.x, a0.y, a0.z, a0.w, a1.x, a1.y, a1.z, a1.w};
        float bv[8] = {bq0.x, bq0.y, bq0.z, bq0.w, bq1.x, bq1.y, bq1.z, bq1.w};
#pragma unroll
        for (int i = 0; i < 8; ++i)
#pragma unroll
            for (int j = 0; j < 8; ++j)
                acc[i][j] = fmaf(av[i], bv[j], acc[i][j]);
    }

    // ---- Epilogue: bias + relu + dot(W2) + tanh; reduce over 8 col-lanes
    float b2v = b2[0];
#pragma unroll
    for (int i = 0; i < 8; ++i) {
        float p = 0.f;
#pragma unroll
        for (int j = 0; j < 8; ++j) {
            int c = tx * 8 + j;
            float h = acc[i][j] + b1s[c];
            p += fmaxf(h, 0.f) * w2s[c];
        }
        p += __shfl_xor(p, 1);
        p += __shfl_xor(p, 2);
        p += __shfl_xor(p, 4);
        if (tx == 0) out[row0 + ty * 8 + i] = tanhf(p + b2v);
    }
}

extern "C" void kernel_launch(void* const* d_in, const int* in_sizes, int n_in,
                              void* d_out, int out_size, void* d_ws, size_t ws_size,
                              hipStream_t stream) {
    const float* emb   = (const float*)d_in[0];
    const int*   ids   = (const int*)d_in[1];
    const float* mask  = (const float*)d_in[2];
    const float* table = (const float*)d_in[3];
    const float* W1    = (const float*)d_in[4];
    const float* b1    = (const float*)d_in[5];
    const float* W2    = (const float*)d_in[6];
    const float* b2    = (const float*)d_in[7];
    float* out = (float*)d_out;
    float* P   = (float*)d_ws;  // 20*64 floats

    compute_P<<<1, 256, 0, stream>>>(table, W1, P);
    const int nblocks = out_size / BM;  // 131072/256 = 512
    scorer_main<<<nblocks, 256, 0, stream>>>(emb, ids, mask, P, W1, b1, W2, b2, out);
}

// Round 2
// 103.734 us; speedup vs baseline: 2.6234x; 2.6234x over previous
//
#include <hip/hip_runtime.h>
#include <math.h>

using short8 = __attribute__((ext_vector_type(8))) short;
using f32x4  = __attribute__((ext_vector_type(4))) float;

#define EMB 768
#define CD  64
#define NSCEN 19
#define KSTEPS 24            // 768 / 32
#define NCHUNKS (25 * 4)     // (24 emb + 1 bag) k-steps x 4 col-tiles, 512 bf16 each

__device__ __forceinline__ ushort f2bf(float x) {
    unsigned u = __float_as_uint(x);
    u += 0x7FFFu + ((u >> 16) & 1u);   // round-to-nearest-even
    return (ushort)(u >> 16);
}

// Pre-fragment B = [W1(768x64) ; P(32x64)] into bf16 wave-chunks of 512 elems:
// chunk c = ks*4+ct; element r = lane*8+j  <->  B[k = ks*32+(lane>>4)*8+j][col = ct*16+(lane&15)]
// P[s][col] = sum_d table[s][d] * W1[768+s*16+d][col]  (s<19), else 0.
__global__ void prep_W1T(const float* __restrict__ table,
                         const float* __restrict__ W1,
                         ushort* __restrict__ W1T) {
    int e = blockIdx.x * 256 + threadIdx.x;      // 0 .. 51200
    if (e >= NCHUNKS * 512) return;
    int chunk = e >> 9, r = e & 511;
    int lane = r >> 3, j = r & 7;
    int ks = chunk >> 2, ct = chunk & 3;
    int col = ct * 16 + (lane & 15);
    int k = ks * 32 + ((lane >> 4) << 3) + j;
    float v = 0.f;
    if (k < EMB) {
        v = W1[(size_t)k * CD + col];
    } else {
        int s = k - EMB;
        if (s < NSCEN) {
            for (int d = 0; d < 16; ++d)
                v += table[s * 16 + d] * W1[(size_t)(EMB + s * 16 + d) * CD + col];
        }
    }
    W1T[e] = f2bf(v);
}

__global__ __launch_bounds__(512, 4)
void scorer_mfma(const float* __restrict__ emb,
                 const int* __restrict__ ids,
                 const float* __restrict__ mask,
                 const ushort* __restrict__ W1T,
                 const float* __restrict__ b1,
                 const float* __restrict__ W2,
                 const float* __restrict__ b2,
                 float* __restrict__ out) {
    __shared__ float  bagf[256][21];   // f32 histogram, stride 21 breaks bank aliasing
    __shared__ ushort bagb[256][32];   // bf16 hist/cnt, zero-padded to K=32

    const int t    = threadIdx.x;
    const int w    = t >> 6;       // wave 0..7, owns rows w*32..w*32+31
    const int lane = t & 63;
    const int lr   = lane & 15;    // A-row / B-col / C-col residue
    const int lg   = lane >> 4;    // k-group (8 wide) / C row-group
    const int row0 = blockIdx.x * 256;

    // ---- bag histogram: thread t owns row t (t<256)
    if (t < 256) {
#pragma unroll
        for (int s = 0; s < NSCEN; ++s) bagf[t][s] = 0.f;
        const int*   idrow = ids  + (size_t)(row0 + t) * 32;
        const float* mrow  = mask + (size_t)(row0 + t) * 32;
        float cnt = 0.f;
#pragma unroll 2
        for (int q = 0; q < 8; ++q) {
            int4   i4 = ((const int4*)idrow)[q];
            float4 m4 = ((const float4*)mrow)[q];
            bagf[t][i4.x] += m4.x; cnt += m4.x;
            bagf[t][i4.y] += m4.y; cnt += m4.y;
            bagf[t][i4.z] += m4.z; cnt += m4.z;
            bagf[t][i4.w] += m4.w; cnt += m4.w;
        }
        float rc = 1.0f / fmaxf(cnt, 1.0f);
#pragma unroll
        for (int s = 0; s < 32; ++s)
            bagb[t][s] = (s < NSCEN) ? f2bf(bagf[t][s] * rc) : (ushort)0;
    }
    __syncthreads();   // the only block barrier

    // ---- barrier-free MFMA stream: 32 rows x 64 cols per wave
    const float* ap = emb + (size_t)(row0 + w * 32 + lr) * EMB + (lg << 3);

    f32x4 acc[2][4];
#pragma unroll
    for (int i = 0; i < 2; ++i)
#pragma unroll
        for (int j = 0; j < 4; ++j) acc[i][j] = (f32x4)0.f;

    float4 a0[2][2], a1[2][2];

#define LOADA(dst, kks) do {                                   \
    const float* _p = ap + (kks) * 32;                         \
    dst[0][0] = *(const float4*)(_p);                          \
    dst[0][1] = *(const float4*)(_p + 4);                      \
    dst[1][0] = *(const float4*)(_p + 16 * EMB);               \
    dst[1][1] = *(const float4*)(_p + 16 * EMB + 4);           \
} while (0)

#define STEP(areg, kks) do {                                               \
    const ushort* _wb = W1T + ((size_t)(kks) << 11) + (lane << 3);         \
    short8 _b0 = *(const short8*)(_wb);                                    \
    short8 _b1 = *(const short8*)(_wb + 512);                              \
    short8 _b2 = *(const short8*)(_wb + 1024);                             \
    short8 _b3 = *(const short8*)(_wb + 1536);                             \
    short8 _a[2];                                                          \
    _Pragma("unroll")                                                      \
    for (int _rt = 0; _rt < 2; ++_rt) {                                    \
        _a[_rt][0] = (short)f2bf(areg[_rt][0].x);                          \
        _a[_rt][1] = (short)f2bf(areg[_rt][0].y);                          \
        _a[_rt][2] = (short)f2bf(areg[_rt][0].z);                          \
        _a[_rt][3] = (short)f2bf(areg[_rt][0].w);                          \
        _a[_rt][4] = (short)f2bf(areg[_rt][1].x);                          \
        _a[_rt][5] = (short)f2bf(areg[_rt][1].y);                          \
        _a[_rt][6] = (short)f2bf(areg[_rt][1].z);                          \
        _a[_rt][7] = (short)f2bf(areg[_rt][1].w);                          \
    }                                                                      \
    _Pragma("unroll")                                                      \
    for (int _rt = 0; _rt < 2; ++_rt) {                                    \
        acc[_rt][0] = __builtin_amdgcn_mfma_f32_16x16x32_bf16(_a[_rt], _b0, acc[_rt][0], 0, 0, 0); \
        acc[_rt][1] = __builtin_amdgcn_mfma_f32_16x16x32_bf16(_a[_rt], _b1, acc[_rt][1], 0, 0, 0); \
        acc[_rt][2] = __builtin_amdgcn_mfma_f32_16x16x32_bf16(_a[_rt], _b2, acc[_rt][2], 0, 0, 0); \
        acc[_rt][3] = __builtin_amdgcn_mfma_f32_16x16x32_bf16(_a[_rt], _b3, acc[_rt][3], 0, 0, 0); \
    }                                                                      \
} while (0)

    LOADA(a0, 0);
#pragma unroll 1
    for (int ks = 0; ks < KSTEPS; ks += 2) {
        LOADA(a1, ks + 1);
        STEP(a0, ks);
        if (ks + 2 < KSTEPS) LOADA(a0, ks + 2);
        STEP(a1, ks + 1);
    }

    // ---- bag k-step (ks = 24): A from LDS (bf16 direct)
    {
        short8 ab[2];
        ab[0] = *(const short8*)&bagb[w * 32 + lr][lg << 3];
        ab[1] = *(const short8*)&bagb[w * 32 + 16 + lr][lg << 3];
        const ushort* wb = W1T + ((size_t)KSTEPS << 11) + (lane << 3);
        short8 b0 = *(const short8*)(wb);
        short8 b1q = *(const short8*)(wb + 512);
        short8 b2q = *(const short8*)(wb + 1024);
        short8 b3q = *(const short8*)(wb + 1536);
#pragma unroll
        for (int rt = 0; rt < 2; ++rt) {
            acc[rt][0] = __builtin_amdgcn_mfma_f32_16x16x32_bf16(ab[rt], b0, acc[rt][0], 0, 0, 0);
            acc[rt][1] = __builtin_amdgcn_mfma_f32_16x16x32_bf16(ab[rt], b1q, acc[rt][1], 0, 0, 0);
            acc[rt][2] = __builtin_amdgcn_mfma_f32_16x16x32_bf16(ab[rt], b2q, acc[rt][2], 0, 0, 0);
            acc[rt][3] = __builtin_amdgcn_mfma_f32_16x16x32_bf16(ab[rt], b3q, acc[rt][3], 0, 0, 0);
        }
    }

    // ---- epilogue: bias + relu + dot(W2) + tanh
    float b1v[4], w2v[4];
#pragma unroll
    for (int ct = 0; ct < 4; ++ct) {
        int c = ct * 16 + lr;
        b1v[ct] = b1[c];
        w2v[ct] = W2[c];
    }
    const float b2v = b2[0];
#pragma unroll
    for (int rt = 0; rt < 2; ++rt) {
#pragma unroll
        for (int r = 0; r < 4; ++r) {
            float p = 0.f;
#pragma unroll
            for (int ct = 0; ct < 4; ++ct) {
                float h = acc[rt][ct][r] + b1v[ct];
                p += fmaxf(h, 0.f) * w2v[ct];
            }
            p += __shfl_xor(p, 1);
            p += __shfl_xor(p, 2);
            p += __shfl_xor(p, 4);
            p += __shfl_xor(p, 8);
            if (lr == 0)
                out[row0 + w * 32 + rt * 16 + (lg << 2) + r] = tanhf(p + b2v);
        }
    }
#undef LOADA
#undef STEP
}

extern "C" void kernel_launch(void* const* d_in, const int* in_sizes, int n_in,
                              void* d_out, int out_size, void* d_ws, size_t ws_size,
                              hipStream_t stream) {
    const float* emb   = (const float*)d_in[0];
    const int*   ids   = (const int*)d_in[1];
    const float* mask  = (const float*)d_in[2];
    const float* table = (const float*)d_in[3];
    const float* W1    = (const float*)d_in[4];
    const float* b1    = (const float*)d_in[5];
    const float* W2    = (const float*)d_in[6];
    const float* b2    = (const float*)d_in[7];
    float* out  = (float*)d_out;
    ushort* W1T = (ushort*)d_ws;   // 51200 bf16 = 100 KB

    prep_W1T<<<200, 256, 0, stream>>>(table, W1, W1T);
    const int nblocks = out_size / 256;   // 512
    scorer_mfma<<<nblocks, 512, 0, stream>>>(emb, ids, mask, W1T, b1, W2, b2, out);
}

// Round 4
// 101.537 us; speedup vs baseline: 2.6802x; 1.0216x over previous
//
#include <hip/hip_runtime.h>
#include <hip/hip_bf16.h>
#include <math.h>

using short8 = __attribute__((ext_vector_type(8))) short;
using f32x4  = __attribute__((ext_vector_type(4))) float;
using fv4    = __attribute__((ext_vector_type(4))) float;

#define EMB 768
#define CD  64
#define NSCEN 19
#define KSTEPS 24            // 768 / 32
#define NCHUNKS (25 * 4)     // (24 emb + 1 bag) k-steps x 4 col-tiles, 512 bf16 each

__device__ __forceinline__ ushort f2bf(float x) {
    unsigned u = __float_as_uint(x);
    u += 0x7FFFu + ((u >> 16) & 1u);   // round-to-nearest-even
    return (ushort)(u >> 16);
}

// packed f32x2 -> bf16x2 via v_cvt_pk_bf16_f32 (compiler emits from the API)
__device__ __forceinline__ uint cvt2(float x, float y) {
    __hip_bfloat162 h = __float22bfloat162_rn(make_float2(x, y));
    union { __hip_bfloat162 h; uint u; } c;
    c.h = h;
    return c.u;
}

// Pre-fragment B = [W1(768x64) ; P(32x64)] into bf16 wave-chunks of 512 elems:
// chunk c = ks*4+ct; element r = lane*8+j  <->  B[k = ks*32+(lane>>4)*8+j][col = ct*16+(lane&15)]
// P[s][col] = sum_d table[s][d] * W1[768+s*16+d][col]  (s<19), else 0.
__global__ void prep_W1T(const float* __restrict__ table,
                         const float* __restrict__ W1,
                         ushort* __restrict__ W1T) {
    int e = blockIdx.x * 256 + threadIdx.x;      // 0 .. 51200
    if (e >= NCHUNKS * 512) return;
    int chunk = e >> 9, r = e & 511;
    int lane = r >> 3, j = r & 7;
    int ks = chunk >> 2, ct = chunk & 3;
    int col = ct * 16 + (lane & 15);
    int k = ks * 32 + ((lane >> 4) << 3) + j;
    float v = 0.f;
    if (k < EMB) {
        v = W1[(size_t)k * CD + col];
    } else {
        int s = k - EMB;
        if (s < NSCEN) {
            for (int d = 0; d < 16; ++d)
                v += table[s * 16 + d] * W1[(size_t)(EMB + s * 16 + d) * CD + col];
        }
    }
    W1T[e] = f2bf(v);
}

__global__ __launch_bounds__(512, 4)
void scorer_mfma(const float* __restrict__ emb,
                 const int* __restrict__ ids,
                 const float* __restrict__ mask,
                 const ushort* __restrict__ W1T,
                 const float* __restrict__ b1,
                 const float* __restrict__ W2,
                 const float* __restrict__ b2,
                 float* __restrict__ out) {
    __shared__ float  bagf[256][21];   // f32 histogram, stride 21 breaks bank aliasing
    __shared__ ushort bagb[256][32];   // bf16 hist/cnt, zero-padded to K=32

    const int t    = threadIdx.x;
    const int w    = t >> 6;       // wave 0..7, owns rows w*32..w*32+31
    const int lane = t & 63;
    const int lr   = lane & 15;    // A-row / B-col residue
    const int lg   = lane >> 4;    // k-group (8 wide) / C row-group
    const int row0 = blockIdx.x * 256;

    // ---- bag histogram: thread t owns row t (t<256)
    if (t < 256) {
#pragma unroll
        for (int s = 0; s < NSCEN; ++s) bagf[t][s] = 0.f;
        const int*   idrow = ids  + (size_t)(row0 + t) * 32;
        const float* mrow  = mask + (size_t)(row0 + t) * 32;
        float cnt = 0.f;
#pragma unroll 2
        for (int q = 0; q < 8; ++q) {
            int4   i4 = ((const int4*)idrow)[q];
            float4 m4 = ((const float4*)mrow)[q];
            bagf[t][i4.x] += m4.x; cnt += m4.x;
            bagf[t][i4.y] += m4.y; cnt += m4.y;
            bagf[t][i4.z] += m4.z; cnt += m4.z;
            bagf[t][i4.w] += m4.w; cnt += m4.w;
        }
        float rc = 1.0f / fmaxf(cnt, 1.0f);
#pragma unroll
        for (int s = 0; s < 32; ++s)
            bagb[t][s] = (s < NSCEN) ? f2bf(bagf[t][s] * rc) : (ushort)0;
    }
    __syncthreads();   // the only block barrier

    // ---- barrier-free MFMA stream: 32 rows x 64 cols per wave
    const float*  ap = emb + (size_t)(row0 + w * 32 + lr) * EMB + (lg << 3);
    const ushort* wp = W1T + (lane << 3);

    f32x4 acc[2][4];
#pragma unroll
    for (int i = 0; i < 2; ++i)
#pragma unroll
        for (int j = 0; j < 4; ++j) acc[i][j] = (f32x4)0.f;

    fv4    aA[2][2], aB[2][2];
    short8 bbA[4], bbB[4];

#define LOADA(dst, kks) do {                                   \
    const float* _p = ap + (kks) * 32;                         \
    dst[0][0] = *(const fv4*)(_p);                             \
    dst[0][1] = *(const fv4*)(_p + 4);                         \
    dst[1][0] = *(const fv4*)(_p + 16 * EMB);                  \
    dst[1][1] = *(const fv4*)(_p + 16 * EMB + 4);              \
} while (0)

#define LOADB(dst, kks) do {                                   \
    const ushort* _q = wp + ((size_t)(kks) << 11);             \
    dst[0] = *(const short8*)(_q);                             \
    dst[1] = *(const short8*)(_q + 512);                       \
    dst[2] = *(const short8*)(_q + 1024);                      \
    dst[3] = *(const short8*)(_q + 1536);                      \
} while (0)

#define STEP(areg, breg) do {                                              \
    short8 _fa[2];                                                         \
    _Pragma("unroll")                                                      \
    for (int _rt = 0; _rt < 2; ++_rt) {                                    \
        union { uint u[4]; short8 s; } _c;                                 \
        _c.u[0] = cvt2(areg[_rt][0][0], areg[_rt][0][1]);                  \
        _c.u[1] = cvt2(areg[_rt][0][2], areg[_rt][0][3]);                  \
        _c.u[2] = cvt2(areg[_rt][1][0], areg[_rt][1][1]);                  \
        _c.u[3] = cvt2(areg[_rt][1][2], areg[_rt][1][3]);                  \
        _fa[_rt] = _c.s;                                                   \
    }                                                                      \
    _Pragma("unroll")                                                      \
    for (int _rt = 0; _rt < 2; ++_rt) {                                    \
        acc[_rt][0] = __builtin_amdgcn_mfma_f32_16x16x32_bf16(_fa[_rt], breg[0], acc[_rt][0], 0, 0, 0); \
        acc[_rt][1] = __builtin_amdgcn_mfma_f32_16x16x32_bf16(_fa[_rt], breg[1], acc[_rt][1], 0, 0, 0); \
        acc[_rt][2] = __builtin_amdgcn_mfma_f32_16x16x32_bf16(_fa[_rt], breg[2], acc[_rt][2], 0, 0, 0); \
        acc[_rt][3] = __builtin_amdgcn_mfma_f32_16x16x32_bf16(_fa[_rt], breg[3], acc[_rt][3], 0, 0, 0); \
    }                                                                      \
} while (0)

    LOADA(aA, 0);
    LOADB(bbA, 0);
#pragma unroll 1
    for (int ks = 0; ks < KSTEPS; ks += 2) {
        LOADA(aB, ks + 1);
        LOADB(bbB, ks + 1);
        STEP(aA, bbA);
        if (ks + 2 < KSTEPS) {
            LOADA(aA, ks + 2);
            LOADB(bbA, ks + 2);
        } else {
            LOADB(bbA, KSTEPS);          // prefetch bag-B chunk
        }
        STEP(aB, bbB);
    }

    // ---- bag k-step (ks = 24): A from LDS (bf16 direct), B = bbA (prefetched)
    {
        short8 ab[2];
        ab[0] = *(const short8*)&bagb[w * 32 + lr][lg << 3];
        ab[1] = *(const short8*)&bagb[w * 32 + 16 + lr][lg << 3];
#pragma unroll
        for (int rt = 0; rt < 2; ++rt) {
            acc[rt][0] = __builtin_amdgcn_mfma_f32_16x16x32_bf16(ab[rt], bbA[0], acc[rt][0], 0, 0, 0);
            acc[rt][1] = __builtin_amdgcn_mfma_f32_16x16x32_bf16(ab[rt], bbA[1], acc[rt][1], 0, 0, 0);
            acc[rt][2] = __builtin_amdgcn_mfma_f32_16x16x32_bf16(ab[rt], bbA[2], acc[rt][2], 0, 0, 0);
            acc[rt][3] = __builtin_amdgcn_mfma_f32_16x16x32_bf16(ab[rt], bbA[3], acc[rt][3], 0, 0, 0);
        }
    }

    // ---- epilogue: bias + relu + dot(W2) + tanh
    float b1v[4], w2v[4];
#pragma unroll
    for (int ct = 0; ct < 4; ++ct) {
        int c = ct * 16 + lr;
        b1v[ct] = b1[c];
        w2v[ct] = W2[c];
    }
    const float b2v = b2[0];
#pragma unroll
    for (int rt = 0; rt < 2; ++rt) {
#pragma unroll
        for (int r = 0; r < 4; ++r) {
            float p = 0.f;
#pragma unroll
            for (int ct = 0; ct < 4; ++ct) {
                float h = acc[rt][ct][r] + b1v[ct];
                p += fmaxf(h, 0.f) * w2v[ct];
            }
            p += __shfl_xor(p, 1);
            p += __shfl_xor(p, 2);
            p += __shfl_xor(p, 4);
            p += __shfl_xor(p, 8);
            if (lr == 0)
                out[row0 + w * 32 + rt * 16 + (lg << 2) + r] = tanhf(p + b2v);
        }
    }
#undef LOADA
#undef LOADB
#undef STEP
}

extern "C" void kernel_launch(void* const* d_in, const int* in_sizes, int n_in,
                              void* d_out, int out_size, void* d_ws, size_t ws_size,
                              hipStream_t stream) {
    const float* emb   = (const float*)d_in[0];
    const int*   ids   = (const int*)d_in[1];
    const float* mask  = (const float*)d_in[2];
    const float* table = (const float*)d_in[3];
    const float* W1    = (const float*)d_in[4];
    const float* b1    = (const float*)d_in[5];
    const float* W2    = (const float*)d_in[6];
    const float* b2    = (const float*)d_in[7];
    float* out  = (float*)d_out;
    ushort* W1T = (ushort*)d_ws;   // 51200 bf16 = 100 KB

    prep_W1T<<<200, 256, 0, stream>>>(table, W1, W1T);
    const int nblocks = out_size / 256;   // 512
    scorer_mfma<<<nblocks, 512, 0, stream>>>(emb, ids, mask, W1T, b1, W2, b2, out);
}